// Round 1
// baseline (913.084 us; speedup 1.0000x reference)
//
#include <hip/hip_runtime.h>
#include <math.h>

#define BB 16384
#define CC 10000
#define DD 256
#define COEF 1.0f
#define CLAMP_MIN 1e-12f
#define CLAMP_MAX 1.0e12f

__global__ void zero_out_kernel(float* out) { out[0] = 0.0f; }

__global__ __launch_bounds__(256) void center_ce_kernel(
    const float* __restrict__ embeddings,
    const float* __restrict__ outputs,
    const int*   __restrict__ target,
    const float* __restrict__ centers,
    float*       __restrict__ out)
{
    const int row  = blockIdx.x;
    const int tid  = threadIdx.x;
    const int lane = tid & 63;
    const int wave = tid >> 6;
    const int t    = target[row];

    // ---- center loss partial: (e_d - c_d)^2, one dim per thread (DD == 256 == blockDim)
    float ed   = embeddings[(size_t)row * DD + tid];
    float cd   = centers[(size_t)t * DD + tid];
    float diff = ed - cd;
    float dsq  = diff * diff;

    // ---- online softmax over outputs[row, :], float4 loads
    const float4* rowp = (const float4*)(outputs + (size_t)row * CC);
    const int n4 = CC / 4;  // 2500
    float m = -INFINITY;
    float s = 0.0f;
    for (int idx = tid; idx < n4; idx += 256) {
        float4 v = rowp[idx];
        float mx = fmaxf(fmaxf(v.x, v.y), fmaxf(v.z, v.w));
        if (mx > m) {
            s *= __expf(m - mx);   // s==0 on first iter, exp(-inf)=0 -> stays 0
            m = mx;
        }
        s += __expf(v.x - m) + __expf(v.y - m) + __expf(v.z - m) + __expf(v.w - m);
    }
    // every thread did >= 9 iterations (2500/256), so m is finite here.

    // ---- wave-level reduction (width 64): combine (m,s) pairs, sum dsq
    for (int off = 32; off > 0; off >>= 1) {
        float om = __shfl_down(m, off, 64);
        float os = __shfl_down(s, off, 64);
        float od = __shfl_down(dsq, off, 64);
        float nm = fmaxf(m, om);
        s = s * __expf(m - nm) + os * __expf(om - nm);
        m = nm;
        dsq += od;
    }

    __shared__ float sm[4], ss[4], sd[4];
    if (lane == 0) { sm[wave] = m; ss[wave] = s; sd[wave] = dsq; }
    __syncthreads();

    if (tid == 0) {
        float M = sm[0], S = ss[0], Dq = sd[0];
        #pragma unroll
        for (int w = 1; w < 4; ++w) {
            float om = sm[w], os = ss[w];
            float nm = fmaxf(M, om);
            S = S * __expf(M - nm) + os * __expf(om - nm);
            M = nm;
            Dq += sd[w];
        }
        float x_t  = outputs[(size_t)row * CC + t];
        float dist = fminf(fmaxf(Dq, CLAMP_MIN), CLAMP_MAX);
        float nll  = -(x_t - M - __logf(S));
        float loss = dist * COEF + nll;
        atomicAdd(out, loss * (1.0f / (float)BB));
    }
}

extern "C" void kernel_launch(void* const* d_in, const int* in_sizes, int n_in,
                              void* d_out, int out_size, void* d_ws, size_t ws_size,
                              hipStream_t stream) {
    const float* embeddings = (const float*)d_in[0];
    const float* outputs    = (const float*)d_in[1];
    const int*   target     = (const int*)  d_in[2];
    const float* centers    = (const float*)d_in[3];
    float* out = (float*)d_out;

    hipLaunchKernelGGL(zero_out_kernel, dim3(1), dim3(1), 0, stream, out);
    hipLaunchKernelGGL(center_ce_kernel, dim3(BB), dim3(256), 0, stream,
                       embeddings, outputs, target, centers, out);
}

// Round 2
// 838.030 us; speedup vs baseline: 1.0896x; 1.0896x over previous
//
#include <hip/hip_runtime.h>
#include <math.h>

#define BB 16384
#define CC 10000
#define DD 256
#define N4 (CC / 4)                 // 2500
#define ROWS_PER_BLOCK 4
#define NBLK (BB / ROWS_PER_BLOCK)  // 4096
#define COEF 1.0f
#define CLAMP_MIN 1e-12f
#define CLAMP_MAX 1.0e12f

// One wave (64 lanes) per batch row; 4 rows per 256-thread block.
__global__ __launch_bounds__(256) void center_ce_kernel(
    const float* __restrict__ embeddings,
    const float* __restrict__ outputs,
    const int*   __restrict__ target,
    const float* __restrict__ centers,
    float*       __restrict__ partials)
{
    const int tid  = threadIdx.x;
    const int lane = tid & 63;
    const int wave = tid >> 6;
    const int row  = blockIdx.x * ROWS_PER_BLOCK + wave;
    const int t    = target[row];

    // ---- center loss: lane i covers dims 4i..4i+3 (DD == 256 == 64 lanes * 4)
    const float4* ep = (const float4*)(embeddings + (size_t)row * DD);
    const float4* cp = (const float4*)(centers    + (size_t)t   * DD);
    float4 e = ep[lane];
    float4 c = cp[lane];
    float dx = e.x - c.x, dy = e.y - c.y, dz = e.z - c.z, dw = e.w - c.w;
    float dsq = dx * dx + dy * dy + dz * dz + dw * dw;

    // ---- online softmax over outputs[row, :], float4 loads, stride 64
    const float4* rowp = (const float4*)(outputs + (size_t)row * CC);
    float m = -INFINITY;
    float s = 0.0f;
    for (int idx = lane; idx < N4; idx += 64) {   // 39 full iters + 4-lane tail
        float4 v = rowp[idx];
        float mx = fmaxf(fmaxf(v.x, v.y), fmaxf(v.z, v.w));
        if (mx > m) { s *= __expf(m - mx); m = mx; }  // s==0 first iter
        s += __expf(v.x - m) + __expf(v.y - m) + __expf(v.z - m) + __expf(v.w - m);
    }

    // ---- wave shuffle reduction of (m, s) and dsq
    for (int off = 32; off > 0; off >>= 1) {
        float om = __shfl_down(m, off, 64);
        float os = __shfl_down(s, off, 64);
        float od = __shfl_down(dsq, off, 64);
        float nm = fmaxf(m, om);
        s = s * __expf(m - nm) + os * __expf(om - nm);
        m = nm;
        dsq += od;
    }

    __shared__ float sl[ROWS_PER_BLOCK];
    if (lane == 0) {
        float x_t  = outputs[(size_t)row * CC + t];
        float dist = fminf(fmaxf(dsq, CLAMP_MIN), CLAMP_MAX);
        float nll  = -(x_t - m - __logf(s));
        sl[wave] = dist * COEF + nll;
    }
    __syncthreads();
    if (tid == 0) {
        float acc = 0.0f;
        #pragma unroll
        for (int w = 0; w < ROWS_PER_BLOCK; ++w) acc += sl[w];
        partials[blockIdx.x] = acc;   // plain store, no atomics
    }
}

__global__ __launch_bounds__(256) void reduce_kernel(
    const float* __restrict__ partials, float* __restrict__ out)
{
    const int tid = threadIdx.x;
    float acc = 0.0f;
    for (int i = tid; i < NBLK; i += 256) acc += partials[i];  // 16 each
    for (int off = 32; off > 0; off >>= 1) acc += __shfl_down(acc, off, 64);
    __shared__ float sw[4];
    if ((tid & 63) == 0) sw[tid >> 6] = acc;
    __syncthreads();
    if (tid == 0) out[0] = (sw[0] + sw[1] + sw[2] + sw[3]) * (1.0f / (float)BB);
}

extern "C" void kernel_launch(void* const* d_in, const int* in_sizes, int n_in,
                              void* d_out, int out_size, void* d_ws, size_t ws_size,
                              hipStream_t stream) {
    const float* embeddings = (const float*)d_in[0];
    const float* outputs    = (const float*)d_in[1];
    const int*   target     = (const int*)  d_in[2];
    const float* centers    = (const float*)d_in[3];
    float* partials = (float*)d_ws;            // 4096 floats = 16 KB of ws
    float* out      = (float*)d_out;

    hipLaunchKernelGGL(center_ce_kernel, dim3(NBLK), dim3(256), 0, stream,
                       embeddings, outputs, target, centers, partials);
    hipLaunchKernelGGL(reduce_kernel, dim3(1), dim3(256), 0, stream,
                       partials, out);
}